// Round 1
// baseline (286.077 us; speedup 1.0000x reference)
//
#include <hip/hip_runtime.h>
#include <hip/hip_bf16.h>

// MMD loss, MI355X. Strategy:
//   three fused RBF-gram reductions via bf16 MFMA 16x16x32, exact diagonal
//   override (exp(0)=1) for the symmetric grams, f32 row-norms from the
//   original f32 data, scalar combine at the end.
//
// ws layout: [sf_bf16 | tf_bf16 | x2s | x2t | w | partials(4 f32)]

typedef short bf16x8 __attribute__((ext_vector_type(8)));
typedef float f32x4 __attribute__((ext_vector_type(4)));

#define D 256  // feature dim (asserted from in_sizes at launch)

static __device__ __forceinline__ unsigned short f32_to_bf16(float f) {
    unsigned int x = __float_as_uint(f);
    unsigned int r = (x + 0x7FFFu + ((x >> 16) & 1u)) >> 16;  // RNE
    return (unsigned short)r;
}

__global__ void init_kernel(float* partials) {
    if (threadIdx.x < 4) partials[threadIdx.x] = 0.0f;
}

// One wave per row: cast to bf16, compute ||row||^2 (f32), gather w, sum w.
__global__ __launch_bounds__(64) void prep_kernel(
    const float* __restrict__ sf, const float* __restrict__ tf,
    const int* __restrict__ lbl, const float* __restrict__ cw,
    unsigned short* __restrict__ sfb, unsigned short* __restrict__ tfb,
    float* __restrict__ x2s, float* __restrict__ x2t,
    float* __restrict__ wv, float* __restrict__ partials, int ns)
{
    int row = blockIdx.x;
    int t = threadIdx.x;
    bool is_src = row < ns;
    int r = is_src ? row : row - ns;
    const float* src = (is_src ? sf : tf) + (size_t)r * D;
    unsigned short* dst = (is_src ? sfb : tfb) + (size_t)r * D;

    float4 v = ((const float4*)src)[t];
    ushort4 u;
    u.x = f32_to_bf16(v.x); u.y = f32_to_bf16(v.y);
    u.z = f32_to_bf16(v.z); u.w = f32_to_bf16(v.w);
    ((ushort4*)dst)[t] = u;

    float s = v.x * v.x + v.y * v.y + v.z * v.z + v.w * v.w;
    #pragma unroll
    for (int off = 32; off; off >>= 1) s += __shfl_xor(s, off);

    if (t == 0) {
        if (is_src) {
            float wi = cw[lbl[r]];
            wv[r] = wi;
            x2s[r] = s;
            atomicAdd(&partials[3], wi);
        } else {
            x2t[r] = s;
        }
    }
}

// MODE 0: Kss weighted (w_i K w_j), diag override.  acc -> partials[0]
// MODE 1: Ktt plain sum, diag override.             acc -> partials[1]
// MODE 2: Kst row-weighted (w_i K),   no diag.      acc -> partials[2]
// Block = 256 threads = 4 waves (2x2), block tile 128x128, wave tile 64x64.
template <int MODE>
__global__ __launch_bounds__(256) void gram_kernel(
    const unsigned short* __restrict__ X, const unsigned short* __restrict__ Y,
    const float* __restrict__ x2x, const float* __restrict__ x2y,
    const float* __restrict__ wv, float* __restrict__ partials, int ntj)
{
    int bi = blockIdx.x / ntj;
    int bj = blockIdx.x % ntj;
    int wid = threadIdx.x >> 6;
    int lane = threadIdx.x & 63;
    int wr = wid >> 1, wc = wid & 1;
    int R0 = bi * 128 + wr * 64;
    int C0 = bj * 128 + wc * 64;
    int lrow = lane & 15;
    int lk = (lane >> 4) * 8;

    f32x4 acc[4][4] = {};
    const unsigned short* xp = X + (size_t)(R0 + lrow) * D + lk;
    const unsigned short* yp = Y + (size_t)(C0 + lrow) * D + lk;

    for (int kk = 0; kk < D; kk += 32) {
        bf16x8 a[4], b[4];
        #pragma unroll
        for (int m = 0; m < 4; ++m)
            a[m] = *(const bf16x8*)(xp + (size_t)m * 16 * D + kk);
        #pragma unroll
        for (int n = 0; n < 4; ++n)
            b[n] = *(const bf16x8*)(yp + (size_t)n * 16 * D + kk);
        #pragma unroll
        for (int m = 0; m < 4; ++m)
            #pragma unroll
            for (int n = 0; n < 4; ++n)
                acc[m][n] = __builtin_amdgcn_mfma_f32_16x16x32_bf16(
                    a[m], b[n], acc[m][n], 0, 0, 0);
    }

    // Epilogue: C/D layout col = lane&15, row = (lane>>4)*4 + reg  [m89/m91]
    int crow = (lane >> 4) * 4;
    int ccol = lane & 15;
    float s = 0.0f;
    #pragma unroll
    for (int m = 0; m < 4; ++m) {
        #pragma unroll
        for (int r = 0; r < 4; ++r) {
            int gr = R0 + 16 * m + crow + r;
            float rx2 = x2x[gr];
            float rw = (MODE != 1) ? wv[gr] : 1.0f;
            #pragma unroll
            for (int n = 0; n < 4; ++n) {
                int gc = C0 + 16 * n + ccol;
                float S = acc[m][n][r];
                float sq = fmaxf(x2y[gc] + rx2 - 2.0f * S, 0.0f);
                float K = __expf(-0.5f * sq);
                if (MODE != 2 && gr == gc) K = 1.0f;  // exact diagonal
                float wf = (MODE == 0) ? rw * wv[gc] : rw;  // MODE1: rw==1
                s += wf * K;
            }
        }
    }
    #pragma unroll
    for (int off = 32; off; off >>= 1) s += __shfl_xor(s, off);
    if (lane == 0) atomicAdd(&partials[MODE], s);
}

__global__ void finalize_kernel(const float* __restrict__ partials,
                                float* __restrict__ out, int nt) {
    float n = partials[3];
    float fnt = (float)nt;
    out[0] = partials[0] / (n * n) + partials[1] / (fnt * fnt)
           - 2.0f * partials[2] / (n * fnt);
}

extern "C" void kernel_launch(void* const* d_in, const int* in_sizes, int n_in,
                              void* d_out, int out_size, void* d_ws, size_t ws_size,
                              hipStream_t stream) {
    const float* sf = (const float*)d_in[0];
    const int* lbl = (const int*)d_in[1];
    const float* tf = (const float*)d_in[2];
    const float* cw = (const float*)d_in[3];
    float* out = (float*)d_out;

    int ns = in_sizes[1];
    int d = in_sizes[0] / ns;   // expect 256
    int nt = in_sizes[2] / d;

    char* p = (char*)d_ws;
    unsigned short* sfb = (unsigned short*)p;  p += (size_t)ns * d * sizeof(unsigned short);
    unsigned short* tfb = (unsigned short*)p;  p += (size_t)nt * d * sizeof(unsigned short);
    float* x2s = (float*)p;                    p += (size_t)ns * sizeof(float);
    float* x2t = (float*)p;                    p += (size_t)nt * sizeof(float);
    float* wv  = (float*)p;                    p += (size_t)ns * sizeof(float);
    float* partials = (float*)p;

    init_kernel<<<1, 64, 0, stream>>>(partials);
    prep_kernel<<<ns + nt, 64, 0, stream>>>(sf, tf, lbl, cw, sfb, tfb,
                                            x2s, x2t, wv, partials, ns);

    int ti_s = ns / 128, ti_t = nt / 128;
    gram_kernel<0><<<ti_s * ti_s, 256, 0, stream>>>(sfb, sfb, x2s, x2s, wv, partials, ti_s);
    gram_kernel<1><<<ti_t * ti_t, 256, 0, stream>>>(tfb, tfb, x2t, x2t, wv, partials, ti_t);
    gram_kernel<2><<<ti_s * ti_t, 256, 0, stream>>>(sfb, tfb, x2s, x2t, wv, partials, ti_t);

    finalize_kernel<<<1, 1, 0, stream>>>(partials, out, nt);
}

// Round 3
// 207.906 us; speedup vs baseline: 1.3760x; 1.3760x over previous
//
#include <hip/hip_runtime.h>
#include <hip/hip_bf16.h>

// MMD loss, MI355X. Round 3 (round-2 fix: name collision b/blk):
//  - single fused gram kernel (modes 0/1/2 decoded from blockIdx)
//  - symmetry: Kss/Ktt only upper-triangle blocks, x2 off-diagonal
//  - __launch_bounds__(256,1) + ping-pong register prefetch so fragment
//    loads pipeline instead of serializing (round-1 VGPR=76 starvation)
//
// ws layout: [sf_bf16 | tf_bf16 | x2s | x2t | w | partials(4 f32)]

typedef short bf16x8 __attribute__((ext_vector_type(8)));
typedef float f32x4 __attribute__((ext_vector_type(4)));

#define D 256  // feature dim (validated from in_sizes at launch)

static __device__ __forceinline__ unsigned short f32_to_bf16(float f) {
    unsigned int x = __float_as_uint(f);
    unsigned int r = (x + 0x7FFFu + ((x >> 16) & 1u)) >> 16;  // RNE
    return (unsigned short)r;
}

// 4 rows per block (one wave per row): cast to bf16, ||row||^2, gather w, sum w.
__global__ __launch_bounds__(256) void prep_kernel(
    const float* __restrict__ sf, const float* __restrict__ tf,
    const int* __restrict__ lbl, const float* __restrict__ cw,
    unsigned short* __restrict__ sfb, unsigned short* __restrict__ tfb,
    float* __restrict__ x2s, float* __restrict__ x2t,
    float* __restrict__ wv, float* __restrict__ partials, int ns)
{
    int row = blockIdx.x * 4 + (threadIdx.x >> 6);
    int t = threadIdx.x & 63;
    bool is_src = row < ns;
    int r = is_src ? row : row - ns;
    const float* src = (is_src ? sf : tf) + (size_t)r * D;
    unsigned short* dst = (is_src ? sfb : tfb) + (size_t)r * D;

    float4 v = ((const float4*)src)[t];
    ushort4 u;
    u.x = f32_to_bf16(v.x); u.y = f32_to_bf16(v.y);
    u.z = f32_to_bf16(v.z); u.w = f32_to_bf16(v.w);
    ((ushort4*)dst)[t] = u;

    float s = v.x * v.x + v.y * v.y + v.z * v.z + v.w * v.w;
    #pragma unroll
    for (int off = 32; off; off >>= 1) s += __shfl_xor(s, off);

    if (t == 0) {
        if (is_src) {
            float wi = cw[lbl[r]];
            wv[r] = wi;
            x2s[r] = s;
            atomicAdd(&partials[3], wi);
        } else {
            x2t[r] = s;
        }
    }
}

// Fused gram kernel. Grid = tri(ti_s) + tri(ti_t) + ti_s*ti_t blocks.
//   mode 0: Kss weighted (w_i K w_j), symmetric, diag override -> partials[0]
//   mode 1: Ktt plain sum,            symmetric, diag override -> partials[1]
//   mode 2: Kst row-weighted (w_i K), full,      no diag       -> partials[2]
// Block = 256 threads = 4 waves (2x2), block tile 128x128, wave tile 64x64.
__global__ __launch_bounds__(256, 1) void gram_kernel(
    const unsigned short* __restrict__ sfb, const unsigned short* __restrict__ tfb,
    const float* __restrict__ x2s, const float* __restrict__ x2t,
    const float* __restrict__ wv, float* __restrict__ partials,
    int ti_s, int ti_t)
{
    int tri_s = ti_s * (ti_s + 1) / 2;
    int tri_t = ti_t * (ti_t + 1) / 2;
    int blk = blockIdx.x;

    int mode, bi, bj;
    const unsigned short *X, *Y;
    const float *x2xp, *x2yp;
    if (blk < tri_s + tri_t) {
        int T, idx;
        if (blk < tri_s) { mode = 0; idx = blk; T = ti_s; X = sfb; Y = sfb; x2xp = x2s; x2yp = x2s; }
        else { mode = 1; idx = blk - tri_s; T = ti_t; X = tfb; Y = tfb; x2xp = x2t; x2yp = x2t; }
        // triangular decode: row bi has (T-bi) blocks, columns bi..T-1
        bi = (int)((2.0f * T + 1.0f -
                    sqrtf((float)((2 * T + 1) * (2 * T + 1) - 8 * idx))) * 0.5f);
        if (bi < 0) bi = 0;
        if (bi > T - 1) bi = T - 1;
        int base = bi * (2 * T - bi + 1) / 2;
        while (base > idx) { --bi; base = bi * (2 * T - bi + 1) / 2; }
        while (idx >= base + (T - bi)) { base += (T - bi); ++bi; }
        bj = bi + (idx - base);
    } else {
        int idx = blk - tri_s - tri_t;
        mode = 2; bi = idx / ti_t; bj = idx % ti_t;
        X = sfb; Y = tfb; x2xp = x2s; x2yp = x2t;
    }
    float factor = (mode != 2 && bi != bj) ? 2.0f : 1.0f;

    int wid = threadIdx.x >> 6;
    int lane = threadIdx.x & 63;
    int wr = wid >> 1, wc = wid & 1;
    int R0 = bi * 128 + wr * 64;
    int C0 = bj * 128 + wc * 64;
    int lrow = lane & 15;
    int lk = (lane >> 4) * 8;

    f32x4 acc[4][4] = {};
    const unsigned short* xp = X + (size_t)(R0 + lrow) * D + lk;
    const unsigned short* yp = Y + (size_t)(C0 + lrow) * D + lk;

    // Ping-pong register prefetch: 8 K-steps of 32, a/b double-buffered.
    bf16x8 af[2][4], bfr[2][4];
    #pragma unroll
    for (int m = 0; m < 4; ++m) {
        af[0][m] = *(const bf16x8*)(xp + (size_t)m * 16 * D);
        bfr[0][m] = *(const bf16x8*)(yp + (size_t)m * 16 * D);
    }
    #pragma unroll
    for (int s = 0; s < 8; ++s) {
        const int cur = s & 1, nxt = cur ^ 1;
        if (s < 7) {
            const int kk = (s + 1) * 32;
            #pragma unroll
            for (int m = 0; m < 4; ++m) {
                af[nxt][m] = *(const bf16x8*)(xp + (size_t)m * 16 * D + kk);
                bfr[nxt][m] = *(const bf16x8*)(yp + (size_t)m * 16 * D + kk);
            }
        }
        #pragma unroll
        for (int m = 0; m < 4; ++m)
            #pragma unroll
            for (int n = 0; n < 4; ++n)
                acc[m][n] = __builtin_amdgcn_mfma_f32_16x16x32_bf16(
                    af[cur][m], bfr[cur][n], acc[m][n], 0, 0, 0);
    }

    // Epilogue: C/D layout col = lane&15, row = (lane>>4)*4 + reg  [m89/m91]
    int crow = (lane >> 4) * 4;
    int ccol = lane & 15;
    float s = 0.0f;
    #pragma unroll
    for (int m = 0; m < 4; ++m) {
        #pragma unroll
        for (int r = 0; r < 4; ++r) {
            int gr = R0 + 16 * m + crow + r;
            float rx2 = x2xp[gr];
            float rw = (mode != 1) ? wv[gr] : 1.0f;
            #pragma unroll
            for (int n = 0; n < 4; ++n) {
                int gc = C0 + 16 * n + ccol;
                float S = acc[m][n][r];
                float sq = fmaxf(x2yp[gc] + rx2 - 2.0f * S, 0.0f);
                float K = __expf(-0.5f * sq);
                if (mode != 2 && gr == gc) K = 1.0f;  // exact diagonal
                float wf = (mode == 0) ? rw * wv[gc] : rw;
                s += wf * K;
            }
        }
    }
    s *= factor;
    #pragma unroll
    for (int off = 32; off; off >>= 1) s += __shfl_xor(s, off);
    if (lane == 0) atomicAdd(&partials[mode], s);
}

__global__ void finalize_kernel(const float* __restrict__ partials,
                                float* __restrict__ out, int nt) {
    float n = partials[3];
    float fnt = (float)nt;
    out[0] = partials[0] / (n * n) + partials[1] / (fnt * fnt)
           - 2.0f * partials[2] / (n * fnt);
}

extern "C" void kernel_launch(void* const* d_in, const int* in_sizes, int n_in,
                              void* d_out, int out_size, void* d_ws, size_t ws_size,
                              hipStream_t stream) {
    const float* sf = (const float*)d_in[0];
    const int* lbl = (const int*)d_in[1];
    const float* tf = (const float*)d_in[2];
    const float* cw = (const float*)d_in[3];
    float* out = (float*)d_out;

    int ns = in_sizes[1];
    int d = in_sizes[0] / ns;   // expect 256
    int nt = in_sizes[2] / d;

    char* p = (char*)d_ws;
    unsigned short* sfb = (unsigned short*)p;  p += (size_t)ns * d * sizeof(unsigned short);
    unsigned short* tfb = (unsigned short*)p;  p += (size_t)nt * d * sizeof(unsigned short);
    float* x2s = (float*)p;                    p += (size_t)ns * sizeof(float);
    float* x2t = (float*)p;                    p += (size_t)nt * sizeof(float);
    float* wv  = (float*)p;                    p += (size_t)ns * sizeof(float);
    float* partials = (float*)p;

    (void)hipMemsetAsync(partials, 0, 4 * sizeof(float), stream);
    prep_kernel<<<(ns + nt) / 4, 256, 0, stream>>>(sf, tf, lbl, cw, sfb, tfb,
                                                   x2s, x2t, wv, partials, ns);

    int ti_s = ns / 128, ti_t = nt / 128;
    int tri_s = ti_s * (ti_s + 1) / 2;
    int tri_t = ti_t * (ti_t + 1) / 2;
    int nblocks = tri_s + tri_t + ti_s * ti_t;
    gram_kernel<<<nblocks, 256, 0, stream>>>(sfb, tfb, x2s, x2t, wv, partials,
                                             ti_s, ti_t);

    finalize_kernel<<<1, 1, 0, stream>>>(partials, out, nt);
}

// Round 4
// 50.327 us; speedup vs baseline: 5.6844x; 4.1311x over previous
//
#include <hip/hip_runtime.h>
#include <hip/hip_bf16.h>

// MMD loss, MI355X. Round 4:
//  - NO ATOMICS anywhere (round-3 diagnosis: ~17ns/same-address atomic
//    serialization dominated both prep and gram kernels). Per-block partial
//    stores + one single-block reduce kernel.
//  - fragment-major bf16 layout written by prep: each MFMA fragment load in
//    gram is one contiguous 1KB wave load (perfect coalescing).
//  - symmetry (upper-triangle blocks x2), fused 3-mode gram kernel,
//    register ping-pong prefetch, __launch_bounds__(256,3).
//
// ws layout: [sfb fragmajor | tfb fragmajor | x2s | x2t | wv | block_out]

typedef short bf16x8 __attribute__((ext_vector_type(8)));
typedef float f32x4 __attribute__((ext_vector_type(4)));

#define D 256  // feature dim (validated from in_sizes at launch)

static __device__ __forceinline__ unsigned short f32_to_bf16(float f) {
    unsigned int x = __float_as_uint(f);
    unsigned int r = (x + 0x7FFFu + ((x >> 16) & 1u)) >> 16;  // RNE
    return (unsigned short)r;
}

// Fragment-major layout: elem (row r, feat k) lives at
//   g = r>>4, rr = r&15, s = k>>5, kr = (k>>3)&3, off = k&7
//   idx = (((g*8 + s)*64) + kr*16 + rr)*8 + off
// so a wave's 64 lanes x 16B fragment load for (g,s) is contiguous 1KB.

// 4 rows per block (one wave per row): cast+swizzle to bf16, ||row||^2, w.
__global__ __launch_bounds__(256) void prep_kernel(
    const float* __restrict__ sf, const float* __restrict__ tf,
    const int* __restrict__ lbl, const float* __restrict__ cw,
    unsigned short* __restrict__ sfb, unsigned short* __restrict__ tfb,
    float* __restrict__ x2s, float* __restrict__ x2t,
    float* __restrict__ wv, int ns)
{
    int row = blockIdx.x * 4 + (threadIdx.x >> 6);
    int t = threadIdx.x & 63;            // lane: handles k = 4t..4t+3
    bool is_src = row < ns;
    int r = is_src ? row : row - ns;
    const float* src = (is_src ? sf : tf) + (size_t)r * D;
    unsigned short* dstb = is_src ? sfb : tfb;

    float4 v = ((const float4*)src)[t];
    ushort4 u;
    u.x = f32_to_bf16(v.x); u.y = f32_to_bf16(v.y);
    u.z = f32_to_bf16(v.z); u.w = f32_to_bf16(v.w);

    int g = r >> 4, rr = r & 15;
    int k = t * 4;
    int s_ = k >> 5, kr = (k >> 3) & 3, off = k & 7;
    size_t idx = ((size_t)((g * 8 + s_) * 64) + kr * 16 + rr) * 8 + off;
    *(ushort4*)(dstb + idx) = u;

    float s = v.x * v.x + v.y * v.y + v.z * v.z + v.w * v.w;
    #pragma unroll
    for (int o = 32; o; o >>= 1) s += __shfl_xor(s, o);

    if (t == 0) {
        if (is_src) { wv[r] = cw[lbl[r]]; x2s[r] = s; }
        else        { x2t[r] = s; }
    }
}

// Fused gram kernel. Grid = tri(ti_s) + tri(ti_t) + ti_s*ti_t blocks.
//   mode 0: Kss weighted (w_i K w_j), symmetric, diag override
//   mode 1: Ktt plain sum,            symmetric, diag override
//   mode 2: Kst row-weighted (w_i K), full,      no diag
// Block = 256 threads = 4 waves (2x2), block tile 128x128, wave tile 64x64.
// Per-block partial -> bout[blk]; no atomics.
__global__ __launch_bounds__(256, 3) void gram_kernel(
    const unsigned short* __restrict__ sfb, const unsigned short* __restrict__ tfb,
    const float* __restrict__ x2s, const float* __restrict__ x2t,
    const float* __restrict__ wv, float* __restrict__ bout,
    int ti_s, int ti_t)
{
    int tri_s = ti_s * (ti_s + 1) / 2;
    int tri_t = ti_t * (ti_t + 1) / 2;
    int blk = blockIdx.x;

    int mode, bi, bj;
    const unsigned short *X, *Y;
    const float *x2xp, *x2yp;
    if (blk < tri_s + tri_t) {
        int T, idx;
        if (blk < tri_s) { mode = 0; idx = blk; T = ti_s; X = sfb; Y = sfb; x2xp = x2s; x2yp = x2s; }
        else { mode = 1; idx = blk - tri_s; T = ti_t; X = tfb; Y = tfb; x2xp = x2t; x2yp = x2t; }
        bi = (int)((2.0f * T + 1.0f -
                    sqrtf((float)((2 * T + 1) * (2 * T + 1) - 8 * idx))) * 0.5f);
        if (bi < 0) bi = 0;
        if (bi > T - 1) bi = T - 1;
        int base = bi * (2 * T - bi + 1) / 2;
        while (base > idx) { --bi; base = bi * (2 * T - bi + 1) / 2; }
        while (idx >= base + (T - bi)) { base += (T - bi); ++bi; }
        bj = bi + (idx - base);
    } else {
        int idx = blk - tri_s - tri_t;
        mode = 2; bi = idx / ti_t; bj = idx % ti_t;
        X = sfb; Y = tfb; x2xp = x2s; x2yp = x2t;
    }
    float factor = (mode != 2 && bi != bj) ? 2.0f : 1.0f;

    int wid = threadIdx.x >> 6;
    int lane = threadIdx.x & 63;
    int wr = wid >> 1, wc = wid & 1;
    int R0 = bi * 128 + wr * 64;
    int C0 = bj * 128 + wc * 64;

    // fragment-major bases: group gA = R0/16, frag (m,s) at XA + (m*8+s)*512
    const unsigned short* XA = X + (size_t)(R0 >> 4) * 4096 + lane * 8;
    const unsigned short* YB = Y + (size_t)(C0 >> 4) * 4096 + lane * 8;

    f32x4 acc[4][4] = {};
    bf16x8 af[2][4], bfr[2][4];
    #pragma unroll
    for (int m = 0; m < 4; ++m) {
        af[0][m]  = *(const bf16x8*)(XA + m * 8 * 512);
        bfr[0][m] = *(const bf16x8*)(YB + m * 8 * 512);
    }
    #pragma unroll
    for (int s = 0; s < 8; ++s) {
        const int cur = s & 1, nxt = cur ^ 1;
        if (s < 7) {
            #pragma unroll
            for (int m = 0; m < 4; ++m) {
                af[nxt][m]  = *(const bf16x8*)(XA + (m * 8 + s + 1) * 512);
                bfr[nxt][m] = *(const bf16x8*)(YB + (m * 8 + s + 1) * 512);
            }
        }
        #pragma unroll
        for (int m = 0; m < 4; ++m)
            #pragma unroll
            for (int n = 0; n < 4; ++n)
                acc[m][n] = __builtin_amdgcn_mfma_f32_16x16x32_bf16(
                    af[cur][m], bfr[cur][n], acc[m][n], 0, 0, 0);
    }

    // Epilogue: C/D layout col = lane&15, row = (lane>>4)*4 + reg  [m89/m91]
    int crow = (lane >> 4) * 4;
    int ccol = lane & 15;
    float s = 0.0f;
    #pragma unroll
    for (int m = 0; m < 4; ++m) {
        #pragma unroll
        for (int r = 0; r < 4; ++r) {
            int gr = R0 + 16 * m + crow + r;
            float rx2 = x2xp[gr];
            float rw = (mode != 1) ? wv[gr] : 1.0f;
            #pragma unroll
            for (int n = 0; n < 4; ++n) {
                int gc = C0 + 16 * n + ccol;
                float S = acc[m][n][r];
                float sq = fmaxf(x2yp[gc] + rx2 - 2.0f * S, 0.0f);
                float K = __expf(-0.5f * sq);
                if (mode != 2 && gr == gc) K = 1.0f;  // exact diagonal
                float wf = (mode == 0) ? rw * wv[gc] : rw;
                s += wf * K;
            }
        }
    }
    s *= factor;
    #pragma unroll
    for (int o = 32; o; o >>= 1) s += __shfl_xor(s, o);

    __shared__ float bsum[4];
    if (lane == 0) bsum[wid] = s;
    __syncthreads();
    if (threadIdx.x == 0)
        bout[blk] = (bsum[0] + bsum[1]) + (bsum[2] + bsum[3]);
}

// Single-block final reduce: n = sum(wv), three mode sums from bout, combine.
__global__ __launch_bounds__(1024) void reduce_kernel(
    const float* __restrict__ wv, int ns,
    const float* __restrict__ bout, int tri_s, int tri_t, int nb,
    float* __restrict__ out, int nt)
{
    int tid = threadIdx.x;
    float n = 0.0f, a0 = 0.0f, a1 = 0.0f, a2 = 0.0f;
    for (int i = tid; i < ns; i += 1024) n += wv[i];
    for (int i = tid; i < nb; i += 1024) {
        float v = bout[i];
        if (i < tri_s) a0 += v;
        else if (i < tri_s + tri_t) a1 += v;
        else a2 += v;
    }
    #pragma unroll
    for (int o = 32; o; o >>= 1) {
        n  += __shfl_xor(n, o);
        a0 += __shfl_xor(a0, o);
        a1 += __shfl_xor(a1, o);
        a2 += __shfl_xor(a2, o);
    }
    __shared__ float ln[16], l0[16], l1[16], l2[16];
    int w = tid >> 6;
    if ((tid & 63) == 0) { ln[w] = n; l0[w] = a0; l1[w] = a1; l2[w] = a2; }
    __syncthreads();
    if (tid == 0) {
        float N = 0, A0 = 0, A1 = 0, A2 = 0;
        #pragma unroll
        for (int i = 0; i < 16; ++i) { N += ln[i]; A0 += l0[i]; A1 += l1[i]; A2 += l2[i]; }
        float fnt = (float)nt;
        out[0] = A0 / (N * N) + A1 / (fnt * fnt) - 2.0f * A2 / (N * fnt);
    }
}

extern "C" void kernel_launch(void* const* d_in, const int* in_sizes, int n_in,
                              void* d_out, int out_size, void* d_ws, size_t ws_size,
                              hipStream_t stream) {
    const float* sf = (const float*)d_in[0];
    const int* lbl = (const int*)d_in[1];
    const float* tf = (const float*)d_in[2];
    const float* cw = (const float*)d_in[3];
    float* out = (float*)d_out;

    int ns = in_sizes[1];
    int d = in_sizes[0] / ns;   // expect 256
    int nt = in_sizes[2] / d;

    char* p = (char*)d_ws;
    unsigned short* sfb = (unsigned short*)p;  p += (size_t)ns * d * sizeof(unsigned short);
    unsigned short* tfb = (unsigned short*)p;  p += (size_t)nt * d * sizeof(unsigned short);
    float* x2s = (float*)p;                    p += (size_t)ns * sizeof(float);
    float* x2t = (float*)p;                    p += (size_t)nt * sizeof(float);
    float* wv  = (float*)p;                    p += (size_t)ns * sizeof(float);
    float* bout = (float*)p;

    prep_kernel<<<(ns + nt) / 4, 256, 0, stream>>>(sf, tf, lbl, cw, sfb, tfb,
                                                   x2s, x2t, wv, ns);

    int ti_s = ns / 128, ti_t = nt / 128;
    int tri_s = ti_s * (ti_s + 1) / 2;
    int tri_t = ti_t * (ti_t + 1) / 2;
    int nblocks = tri_s + tri_t + ti_s * ti_t;
    gram_kernel<<<nblocks, 256, 0, stream>>>(sfb, tfb, x2s, x2t, wv, bout,
                                             ti_s, ti_t);

    reduce_kernel<<<1, 1024, 0, stream>>>(wv, ns, bout, tri_s, tri_t, nblocks,
                                          out, nt);
}